// Round 8
// baseline (139.019 us; speedup 1.0000x reference)
//
#include <hip/hip_runtime.h>
#include <stdint.h>

// Problem constants (fixed by the reference)
#define B_      16
#define N_      2048
#define M_      8192
#define ROWS    (B_ * N_)        // 32768
#define D_      8                // 4*2 flattened

// Single-kernel tiling: block = 256 threads = 4 waves; each wave owns 8 rows
// (wave-uniform -> held in SGPRs); lanes scan disjoint anchors.
#define BLK     256
#define RPW     8                // rows per wave (in SGPRs, uniform across lanes)
#define WPB     4                // waves per block
#define RPB     (RPW * WPB)      // 32 rows per block
#define NBLK    (ROWS / RPB)     // 1024 blocks -> 4 blocks/CU resident
#define CHUNK   512              // anchors staged per LDS chunk
#define NCHUNK  (M_ / CHUNK)     // 16
#define STEPS   (CHUNK / 64)     // 8 lane-strided steps per chunk
#define PFPT    (CHUNK / BLK)    // 2 anchors prefetched per thread

typedef float v2f __attribute__((ext_vector_type(2)));

// Force a wave-uniform float into an SGPR (bit-exact: value identical on all lanes).
__device__ __forceinline__ float rfl(float v) {
    return __int_as_float(__builtin_amdgcn_readfirstlane(__float_as_int(v)));
}

// LDS: single buffer, separate float4 arrays (16B-aligned lane-contiguous
// ds_read_b128, conflict-free). 18KB -> 4 blocks/CU = 72KB.
// Hot loop per (anchor, row): v_pk_mul_f32 + 3x v_pk_fma_f32 (the 157-TF
// packed fp32 pipe; scalar v_fma_f32 ceiling is only ~78 TF) + 2 adds +
// cmp + 2 cndmask = 9 instr. X operands are SGPR pairs (1 SGPR read/instr is
// architecturally free).
__global__ __launch_bounds__(BLK, 4) void colddiff_kernel(
    const float* __restrict__ x,        // [ROWS][8]
    const float* __restrict__ anchors,  // [M_][8]
    const float* __restrict__ sa_tab,   // [1000]
    const float* __restrict__ sb_tab,   // [1000]
    const int*   __restrict__ t,        // [B_]
    float* __restrict__ out)            // [ROWS][8]
{
    __shared__ float4 sA0[CHUNK];       // anchor floats 0..3 (raw)
    __shared__ float4 sA1[CHUNK];       // anchor floats 4..7 (raw)
    __shared__ float  sH [CHUNK];       // 0.5*||a||^2

    const int tid  = threadIdx.x;
    const int lane = tid & 63;
    const int wave = tid >> 6;
    const int rowbase = blockIdx.x * RPB + wave * RPW;

    // My wave's 8 rows, NEGATED, as wave-uniform float2 pairs in SGPRs.
    v2f Xp[RPW][4];
    #pragma unroll
    for (int r = 0; r < RPW; ++r) {
        const float4* px = (const float4*)(x + (size_t)(rowbase + r) * D_);
        const float4 lo = px[0], hi = px[1];
        Xp[r][0] = (v2f){rfl(-lo.x), rfl(-lo.y)};
        Xp[r][1] = (v2f){rfl(-lo.z), rfl(-lo.w)};
        Xp[r][2] = (v2f){rfl(-hi.x), rfl(-hi.y)};
        Xp[r][3] = (v2f){rfl(-hi.z), rfl(-hi.w)};
    }

    float best[RPW];
    int   bidx[RPW];
    #pragma unroll
    for (int r = 0; r < RPW; ++r) { best[r] = 3.4e38f; bidx[r] = 0; }

    // Prefetch chunk 0 into registers (4 float4 = 16 VGPRs)
    const float4* gA = (const float4*)anchors;
    float4 p0[PFPT], p1[PFPT];
    #pragma unroll
    for (int i = 0; i < PFPT; ++i) {
        const int slot = tid + i * BLK;
        p0[i] = gA[2 * slot];
        p1[i] = gA[2 * slot + 1];
    }

    for (int c = 0; c < NCHUNK; ++c) {
        __syncthreads();                 // LDS of chunk c-1 fully consumed
        // Write prefetched chunk c to LDS (+ half-norms from registers)
        #pragma unroll
        for (int i = 0; i < PFPT; ++i) {
            const int slot = tid + i * BLK;
            const float4 a0 = p0[i], a1 = p1[i];
            float nr = a0.x * a0.x;
            nr = fmaf(a0.y, a0.y, nr);
            nr = fmaf(a0.z, a0.z, nr);
            nr = fmaf(a0.w, a0.w, nr);
            nr = fmaf(a1.x, a1.x, nr);
            nr = fmaf(a1.y, a1.y, nr);
            nr = fmaf(a1.z, a1.z, nr);
            nr = fmaf(a1.w, a1.w, nr);
            sA0[slot] = a0;
            sA1[slot] = a1;
            sH [slot] = 0.5f * nr;
        }
        __syncthreads();
        // Issue next chunk's global loads; they drain during compute below
        if (c + 1 < NCHUNK) {
            #pragma unroll
            for (int i = 0; i < PFPT; ++i) {
                const int slot = (c + 1) * CHUNK + tid + i * BLK;
                p0[i] = gA[2 * slot];
                p1[i] = gA[2 * slot + 1];
            }
        }
        // Hot loop
        #pragma unroll 2
        for (int k = 0; k < STEPS; ++k) {
            const int slot = k * 64 + lane;          // lane-contiguous b128
            const float4 a0 = sA0[slot];
            const float4 a1 = sA1[slot];
            const float  hn = sH [slot];
            const int    j  = c * CHUNK + slot;
            const v2f A01 = (v2f){a0.x, a0.y};
            const v2f A23 = (v2f){a0.z, a0.w};
            const v2f A45 = (v2f){a1.x, a1.y};
            const v2f A67 = (v2f){a1.z, a1.w};
            #pragma unroll
            for (int r = 0; r < RPW; ++r) {
                v2f acc = Xp[r][0] * A01;                            // v_pk_mul_f32
                acc = __builtin_elementwise_fma(Xp[r][1], A23, acc); // v_pk_fma_f32
                acc = __builtin_elementwise_fma(Xp[r][2], A45, acc);
                acc = __builtin_elementwise_fma(Xp[r][3], A67, acc);
                const float s = (hn + acc.x) + acc.y;                // hn - x.a
                // strict '<' + ascending j => lowest index kept on ties
                const bool cc = s < best[r];
                best[r] = cc ? s : best[r];
                bidx[r] = cc ? j : bidx[r];
            }
        }
    }

    // Per-wave lexicographic (score, idx) butterfly min; idx tie-break ==
    // jnp.argmin first-occurrence (lanes hold disjoint ascending j sets).
    #pragma unroll
    for (int r = 0; r < RPW; ++r) {
        #pragma unroll
        for (int m = 1; m < 64; m <<= 1) {
            const float ov = __shfl_xor(best[r], m);
            const int   oj = __shfl_xor(bidx[r], m);
            const bool take = (ov < best[r]) || (ov == best[r] && oj < bidx[r]);
            best[r] = take ? ov : best[r];
            bidx[r] = take ? oj : bidx[r];
        }
    }

    // Lanes 0..7 each emit one row (fused q_sample epilogue).
    if (lane < RPW) {
        int selj = bidx[0];
        #pragma unroll
        for (int r = 1; r < RPW; ++r) selj = (lane == r) ? bidx[r] : selj;

        const int row = rowbase + lane;
        const int tb  = t[row >> 11];               // row / N_
        const float sa = sa_tab[tb];
        const float sb = sb_tab[tb];

        const float4* px = (const float4*)(x + (size_t)row * D_);
        const float4* pa = (const float4*)(anchors + (size_t)selj * D_);
        const float4 x0 = px[0], x1 = px[1];
        const float4 a0 = pa[0], a1 = pa[1];

        float4 o0, o1;
        o0.x = fmaf(sa, x0.x, sb * a0.x);
        o0.y = fmaf(sa, x0.y, sb * a0.y);
        o0.z = fmaf(sa, x0.z, sb * a0.z);
        o0.w = fmaf(sa, x0.w, sb * a0.w);
        o1.x = fmaf(sa, x1.x, sb * a1.x);
        o1.y = fmaf(sa, x1.y, sb * a1.y);
        o1.z = fmaf(sa, x1.z, sb * a1.z);
        o1.w = fmaf(sa, x1.w, sb * a1.w);

        float4* po = (float4*)(out + (size_t)row * D_);
        po[0] = o0;
        po[1] = o1;
    }
}

extern "C" void kernel_launch(void* const* d_in, const int* in_sizes, int n_in,
                              void* d_out, int out_size, void* d_ws, size_t ws_size,
                              hipStream_t stream) {
    const float* x       = (const float*)d_in[0];  // x_start [16,2048,4,2]
    const float* anchors = (const float*)d_in[1];  // anchors [8192,4,2]
    const float* sa_tab  = (const float*)d_in[2];  // sqrt_alphas_cumprod [1000]
    const float* sb_tab  = (const float*)d_in[3];  // sqrt_one_minus_alphas_cumprod [1000]
    const int*   t       = (const int*)d_in[4];    // t [16]
    float* out = (float*)d_out;

    colddiff_kernel<<<NBLK, BLK, 0, stream>>>(x, anchors, sa_tab, sb_tab, t, out);
}

// Round 9
// 137.359 us; speedup vs baseline: 1.0121x; 1.0121x over previous
//
#include <hip/hip_runtime.h>
#include <stdint.h>

// Problem constants (fixed by the reference)
#define B_      16
#define N_      2048
#define M_      8192
#define ROWS    (B_ * N_)        // 32768
#define D_      8                // 4*2 flattened

// Split-K tiling: block = 256 threads = 4 waves = 2 row-groups x 2 anchor-
// halves. Each wave: 8 rows (SGPR-resident), half of every chunk's anchors.
// 2048 blocks -> 8 blocks/CU -> 8 waves/SIMD (vs 4 before): desynchronized
// barriers + 2x latency hiding.
#define BLK     256
#define RPW     8                // rows per group (in SGPRs, wave-uniform)
#define RPB     16               // rows per block (2 groups)
#define NBLK    (ROWS / RPB)     // 2048 blocks
#define CHUNK   512              // anchors staged per LDS chunk
#define NCHUNK  (M_ / CHUNK)     // 16
#define KSTEPS  4                // k-steps per wave per chunk (half of CHUNK/64)
#define PFPT    (CHUNK / BLK)    // 2 anchors prefetched per thread

// Force a wave-uniform float into an SGPR (bit-exact; value identical on all lanes).
__device__ __forceinline__ float rfl(float v) {
    return __int_as_float(__builtin_amdgcn_readfirstlane(__float_as_int(v)));
}

// LDS: 8KB + 8KB + 2KB anchors + 256B combine = 18.75KB -> 8 blocks/CU = 150KB.
// Hot loop per (anchor,row): 8x v_fma_f32 (SGPR x-operand) + cmp + 2 cndmask.
__global__ __launch_bounds__(BLK, 8) void colddiff_kernel(
    const float* __restrict__ x,        // [ROWS][8]
    const float* __restrict__ anchors,  // [M_][8]
    const float* __restrict__ sa_tab,   // [1000]
    const float* __restrict__ sb_tab,   // [1000]
    const int*   __restrict__ t,        // [B_]
    float* __restrict__ out)            // [ROWS][8]
{
    __shared__ float4 sA0[CHUNK];       // anchor floats 0..3 (raw)
    __shared__ float4 sA1[CHUNK];       // anchor floats 4..7 (raw)
    __shared__ float  sH [CHUNK];       // 0.5*||a||^2
    __shared__ float  sV [4 * RPW];     // per-(wave,row) best value
    __shared__ int    sI [4 * RPW];     // per-(wave,row) best index

    const int tid   = threadIdx.x;
    const int lane  = tid & 63;
    const int wave  = tid >> 6;
    const int group = wave >> 1;        // row-group 0/1
    const int khalf = wave & 1;         // anchor half 0/1
    const int rowbase = blockIdx.x * RPB + group * RPW;

    // My group's 8 rows, NEGATED, into SGPRs (fmaf(-x,a,.) == fmaf(x,-a,.)).
    float Xs[RPW][D_];
    #pragma unroll
    for (int r = 0; r < RPW; ++r) {
        const float4* px = (const float4*)(x + (size_t)(rowbase + r) * D_);
        const float4 lo = px[0], hi = px[1];
        Xs[r][0] = rfl(-lo.x); Xs[r][1] = rfl(-lo.y);
        Xs[r][2] = rfl(-lo.z); Xs[r][3] = rfl(-lo.w);
        Xs[r][4] = rfl(-hi.x); Xs[r][5] = rfl(-hi.y);
        Xs[r][6] = rfl(-hi.z); Xs[r][7] = rfl(-hi.w);
    }

    float best[RPW];
    int   bidx[RPW];
    #pragma unroll
    for (int r = 0; r < RPW; ++r) { best[r] = 3.4e38f; bidx[r] = 0; }

    // Prefetch chunk 0 into registers (4 float4 = 16 VGPRs)
    const float4* gA = (const float4*)anchors;
    float4 p0[PFPT], p1[PFPT];
    #pragma unroll
    for (int i = 0; i < PFPT; ++i) {
        const int slot = tid + i * BLK;
        p0[i] = gA[2 * slot];
        p1[i] = gA[2 * slot + 1];
    }

    for (int c = 0; c < NCHUNK; ++c) {
        __syncthreads();                 // LDS of chunk c-1 fully consumed
        // Write prefetched chunk c to LDS (+ half-norms from registers)
        #pragma unroll
        for (int i = 0; i < PFPT; ++i) {
            const int slot = tid + i * BLK;
            const float4 a0 = p0[i], a1 = p1[i];
            float nr = a0.x * a0.x;
            nr = fmaf(a0.y, a0.y, nr);
            nr = fmaf(a0.z, a0.z, nr);
            nr = fmaf(a0.w, a0.w, nr);
            nr = fmaf(a1.x, a1.x, nr);
            nr = fmaf(a1.y, a1.y, nr);
            nr = fmaf(a1.z, a1.z, nr);
            nr = fmaf(a1.w, a1.w, nr);
            sA0[slot] = a0;
            sA1[slot] = a1;
            sH [slot] = 0.5f * nr;
        }
        __syncthreads();
        // Issue next chunk's global loads; they drain during compute below
        if (c + 1 < NCHUNK) {
            #pragma unroll
            for (int i = 0; i < PFPT; ++i) {
                const int slot = (c + 1) * CHUNK + tid + i * BLK;
                p0[i] = gA[2 * slot];
                p1[i] = gA[2 * slot + 1];
            }
        }
        // Hot loop: this wave's half of the chunk (lane-contiguous b128)
        #pragma unroll 2
        for (int k = 0; k < KSTEPS; ++k) {
            const int slot = khalf * (CHUNK / 2) + k * 64 + lane;
            const float4 a0 = sA0[slot];
            const float4 a1 = sA1[slot];
            const float  hn = sH [slot];
            const int    j  = c * CHUNK + slot;
            #pragma unroll
            for (int r = 0; r < RPW; ++r) {
                float s = fmaf(Xs[r][0], a0.x, hn);  // hn - x.a
                s = fmaf(Xs[r][1], a0.y, s);
                s = fmaf(Xs[r][2], a0.z, s);
                s = fmaf(Xs[r][3], a0.w, s);
                s = fmaf(Xs[r][4], a1.x, s);
                s = fmaf(Xs[r][5], a1.y, s);
                s = fmaf(Xs[r][6], a1.z, s);
                s = fmaf(Xs[r][7], a1.w, s);
                // strict '<' + ascending j per lane => lowest index on ties
                const bool cc = s < best[r];
                best[r] = cc ? s : best[r];
                bidx[r] = cc ? j : bidx[r];
            }
        }
    }

    // Per-wave lexicographic (score, idx) butterfly min; idx tie-break ==
    // jnp.argmin first-occurrence (lanes hold disjoint ascending j sets).
    #pragma unroll
    for (int r = 0; r < RPW; ++r) {
        #pragma unroll
        for (int m = 1; m < 64; m <<= 1) {
            const float ov = __shfl_xor(best[r], m);
            const int   oj = __shfl_xor(bidx[r], m);
            const bool take = (ov < best[r]) || (ov == best[r] && oj < bidx[r]);
            best[r] = take ? ov : best[r];
            bidx[r] = take ? oj : bidx[r];
        }
    }

    // Lanes 0..7 publish this wave's per-row winner to LDS.
    if (lane < RPW) {
        float selv = best[0];
        int   selj = bidx[0];
        #pragma unroll
        for (int r = 1; r < RPW; ++r) {
            const bool m = (lane == r);
            selv = m ? best[r] : selv;
            selj = m ? bidx[r] : selj;
        }
        sV[wave * RPW + lane] = selv;
        sI[wave * RPW + lane] = selj;
    }
    __syncthreads();

    // Threads 0..15: combine the two anchor-halves (lexicographic — halves
    // interleave across chunks so compare idx, not wave id) + fused epilogue.
    if (tid < RPB) {
        const int grp = tid >> 3;
        const int r   = tid & 7;
        const float vA = sV[(2 * grp) * RPW + r];
        const int   iA = sI[(2 * grp) * RPW + r];
        const float vB = sV[(2 * grp + 1) * RPW + r];
        const int   iB = sI[(2 * grp + 1) * RPW + r];
        const bool take = (vB < vA) || (vB == vA && iB < iA);
        const int bi = take ? iB : iA;

        const int row = blockIdx.x * RPB + tid;     // grp*8 + r == tid
        const int tb  = t[row >> 11];               // row / N_
        const float sa = sa_tab[tb];
        const float sb = sb_tab[tb];

        const float4* px = (const float4*)(x + (size_t)row * D_);
        const float4* pa = (const float4*)(anchors + (size_t)bi * D_);
        const float4 x0 = px[0], x1 = px[1];
        const float4 a0 = pa[0], a1 = pa[1];

        float4 o0, o1;
        o0.x = fmaf(sa, x0.x, sb * a0.x);
        o0.y = fmaf(sa, x0.y, sb * a0.y);
        o0.z = fmaf(sa, x0.z, sb * a0.z);
        o0.w = fmaf(sa, x0.w, sb * a0.w);
        o1.x = fmaf(sa, x1.x, sb * a1.x);
        o1.y = fmaf(sa, x1.y, sb * a1.y);
        o1.z = fmaf(sa, x1.z, sb * a1.z);
        o1.w = fmaf(sa, x1.w, sb * a1.w);

        float4* po = (float4*)(out + (size_t)row * D_);
        po[0] = o0;
        po[1] = o1;
    }
}

extern "C" void kernel_launch(void* const* d_in, const int* in_sizes, int n_in,
                              void* d_out, int out_size, void* d_ws, size_t ws_size,
                              hipStream_t stream) {
    const float* x       = (const float*)d_in[0];  // x_start [16,2048,4,2]
    const float* anchors = (const float*)d_in[1];  // anchors [8192,4,2]
    const float* sa_tab  = (const float*)d_in[2];  // sqrt_alphas_cumprod [1000]
    const float* sb_tab  = (const float*)d_in[3];  // sqrt_one_minus_alphas_cumprod [1000]
    const int*   t       = (const int*)d_in[4];    // t [16]
    float* out = (float*)d_out;

    colddiff_kernel<<<NBLK, BLK, 0, stream>>>(x, anchors, sa_tab, sb_tab, t, out);
}